// Round 11
// baseline (71.577 us; speedup 1.0000x reference)
//
#include <hip/hip_runtime.h>
#include <hip/hip_fp16.h>

#define CDIM 512
#define ROWS 65536
#define BM   256

typedef _Float16 half8  __attribute__((ext_vector_type(8)));
typedef __fp16   fp16x2 __attribute__((ext_vector_type(2)));
typedef float    f32x16 __attribute__((ext_vector_type(16)));

// async global->LDS, 16B per lane; LDS dest = wave-uniform base (+ lane*16 implicit)
#define GLD_LDS16(gp, lp) __builtin_amdgcn_global_load_lds( \
    (const __attribute__((address_space(1))) unsigned int*)(gp), \
    (__attribute__((address_space(3))) unsigned int*)(lp), 16, 0, 0)

__device__ __forceinline__ half8 cvt8(float4 f0, float4 f1) {
    union { fp16x2 h2[4]; half8 h8; } u;
    u.h2[0] = __builtin_amdgcn_cvt_pkrtz(f0.x, f0.y);
    u.h2[1] = __builtin_amdgcn_cvt_pkrtz(f0.z, f0.w);
    u.h2[2] = __builtin_amdgcn_cvt_pkrtz(f1.x, f1.y);
    u.h2[3] = __builtin_amdgcn_cvt_pkrtz(f1.z, f1.w);
    return u.h8;
}

// ---------------- K1 (fused): blocks 0..31 qproj, blocks 32..159 wkfrag ----------------
__global__ void prep_kernel(const float* __restrict__ Q, const float* __restrict__ Wq,
                            const float* __restrict__ bq, const float* __restrict__ Wout,
                            const float* __restrict__ Wk,
                            float* __restrict__ v, _Float16* __restrict__ Wkf) {
    __shared__ float qs[CDIM];
    const int t = threadIdx.x;
    if (blockIdx.x < 32) {
        // v[j] = relu(Q.Wq[j,:]+bq[j]) * Wout[j/64] / 8 ; bout dropped (softmax shift-invariant)
        qs[t] = Q[t]; qs[t + 256] = Q[t + 256];
        __syncthreads();
        const int jj  = t >> 4;
        const int sub = t & 15;
        const int j   = blockIdx.x * 16 + jj;
        const float4* w4 = (const float4*)(Wq + (size_t)j * CDIM + sub * 32);
        const float4* q4 = (const float4*)(qs + sub * 32);
        float s = 0.f;
        #pragma unroll
        for (int i = 0; i < 8; ++i) {
            float4 w = w4[i]; float4 q = q4[i];
            s = fmaf(w.x, q.x, s); s = fmaf(w.y, q.y, s);
            s = fmaf(w.z, q.z, s); s = fmaf(w.w, q.w, s);
        }
        s += __shfl_xor(s, 1); s += __shfl_xor(s, 2);
        s += __shfl_xor(s, 4); s += __shfl_xor(s, 8);
        if (sub == 0) {
            s += bq[j];
            s = fmaxf(s, 0.f);
            v[j] = s * Wout[j >> 6] * 0.125f;
        }
    } else {
        // Wk -> fp16 B-fragments [jb 0..15][kc 0..31][lane 0..63][8 halfs]
        // frag(jb,kc) lane l: B[k=kc*16+(l>>5)*8+e][j=jb*32+(l&31)]
        const int gid = (blockIdx.x - 32) * 256 + t;
        const int jb  = gid >> 11;
        const int kc  = (gid >> 6) & 31;
        const int l   = gid & 63;
        const int j   = jb * 32 + (l & 31);
        const int k   = kc * 16 + (l >> 5) * 8;
        const float* src = Wk + (size_t)j * CDIM + k;
        float4 f0 = *(const float4*)(src);
        float4 f1 = *(const float4*)(src + 4);
        *(half8*)(Wkf + (size_t)gid * 8) = cvt8(f0, f1);
    }
}

// ---------------- K2: big-tile fused GEMM: BM=256 x BN=256(class) x BK=64 ----------------
// grid (256, 2); 512 thr = 8 waves, wave = (wm = w>>2) x (wn = w&3): 128 rows x 64 j.
// acc[4][2] f32x16. A: reg-staged fp32->fp16 frag-major LDS (2x32KB dbuf).
// B: global_load_lds from frag-major Wkf (2x32KB dbuf). 1 barrier per K-step.
// Epilogue ONCE: relu+v fold-tree per mb, cross-wave LDS sum -> partial2[cls].
__global__ __launch_bounds__(512, 1) void score_kernel(
    const float* __restrict__ Kmat, const _Float16* __restrict__ Wkf,
    const float* __restrict__ bk, const float* __restrict__ v,
    float* __restrict__ partial2)
{
    __shared__ alignas(16) char Ab[2][32768];   // frag(MB 0..7, kc 0..3) @ (MB*4+kc)*1024
    __shared__ alignas(16) char Bbuf[2][32768]; // frag(nb 0..7, kc 0..3) @ (nb*4+kc)*1024
    __shared__ float scr[2][4][128];

    const int tid  = threadIdx.x;
    const int lane = tid & 63;
    const int wave = tid >> 6;
    const int l31  = lane & 31;
    const int lhi  = lane >> 5;
    const int wm   = wave >> 2;
    const int wn   = wave & 3;
    const int cls  = blockIdx.y;
    const int rowbase = blockIdx.x * BM;

    // A staging: thread owns frag MB=wave: row = rowbase + wave*32 + l31, k-half lhi*8
    const float* gA = Kmat + (size_t)(rowbase + wave * 32 + l31) * CDIM + lhi * 8;
    // B staging: wave issues nb=wave, kcl 0..3
    const _Float16* gB = Wkf + ((size_t)(cls * 8 + wave) * 32) * 512;  // frag(jb,0) base; +kcg*512 halfs

    f32x16 acc[4][2];
    #pragma unroll
    for (int mb = 0; mb < 4; ++mb)
        #pragma unroll
        for (int b = 0; b < 2; ++b)
            #pragma unroll
            for (int r = 0; r < 16; ++r) acc[mb][b][r] = 0.f;

    // ---- prologue: stage tile 0 (A direct, B DMA), load R = A(1) ----
    #pragma unroll
    for (int kc = 0; kc < 4; ++kc) {
        float4 f0 = *(const float4*)(gA + kc * 16);
        float4 f1 = *(const float4*)(gA + kc * 16 + 4);
        *(half8*)(Ab[0] + (wave * 4 + kc) * 1024 + lane * 16) = cvt8(f0, f1);
        GLD_LDS16(gB + (size_t)kc * 512 + lane * 8, Bbuf[0] + (wave * 4 + kc) * 1024);
    }
    float4 R[4][2];
    #pragma unroll
    for (int kc = 0; kc < 4; ++kc) {
        R[kc][0] = *(const float4*)(gA + 64 + kc * 16);
        R[kc][1] = *(const float4*)(gA + 64 + kc * 16 + 4);
    }
    __syncthreads();

    #pragma unroll
    for (int ks = 0; ks < 8; ++ks) {
        const int cur = ks & 1;
        // ---- staging for ks+1 (writes from R loaded last iter; B via async DMA) ----
        if (ks < 7) {
            #pragma unroll
            for (int kc = 0; kc < 4; ++kc) {
                *(half8*)(Ab[cur ^ 1] + (wave * 4 + kc) * 1024 + lane * 16)
                    = cvt8(R[kc][0], R[kc][1]);
                GLD_LDS16(gB + (size_t)((ks + 1) * 4 + kc) * 512 + lane * 8,
                          Bbuf[cur ^ 1] + (wave * 4 + kc) * 1024);
            }
        }
        // ---- issue R loads for ks+2 (a full K-step of latency cover) ----
        if (ks < 6) {
            #pragma unroll
            for (int kc = 0; kc < 4; ++kc) {
                R[kc][0] = *(const float4*)(gA + (ks + 2) * 64 + kc * 16);
                R[kc][1] = *(const float4*)(gA + (ks + 2) * 64 + kc * 16 + 4);
            }
        }
        __builtin_amdgcn_sched_barrier(0);
        // ---- compute: 4 kc x (4 a-frags, 2 b-frags) x 8 MFMA ----
        #pragma unroll
        for (int kc = 0; kc < 4; ++kc) {
            half8 a0 = *(const half8*)(Ab[cur] + ((wm * 4 + 0) * 4 + kc) * 1024 + lane * 16);
            half8 a1 = *(const half8*)(Ab[cur] + ((wm * 4 + 1) * 4 + kc) * 1024 + lane * 16);
            half8 a2 = *(const half8*)(Ab[cur] + ((wm * 4 + 2) * 4 + kc) * 1024 + lane * 16);
            half8 a3 = *(const half8*)(Ab[cur] + ((wm * 4 + 3) * 4 + kc) * 1024 + lane * 16);
            half8 b0 = *(const half8*)(Bbuf[cur] + ((wn * 2 + 0) * 4 + kc) * 1024 + lane * 16);
            half8 b1 = *(const half8*)(Bbuf[cur] + ((wn * 2 + 1) * 4 + kc) * 1024 + lane * 16);
            acc[0][0] = __builtin_amdgcn_mfma_f32_32x32x16_f16(a0, b0, acc[0][0], 0, 0, 0);
            acc[1][0] = __builtin_amdgcn_mfma_f32_32x32x16_f16(a1, b0, acc[1][0], 0, 0, 0);
            acc[2][0] = __builtin_amdgcn_mfma_f32_32x32x16_f16(a2, b0, acc[2][0], 0, 0, 0);
            acc[3][0] = __builtin_amdgcn_mfma_f32_32x32x16_f16(a3, b0, acc[3][0], 0, 0, 0);
            acc[0][1] = __builtin_amdgcn_mfma_f32_32x32x16_f16(a0, b1, acc[0][1], 0, 0, 0);
            acc[1][1] = __builtin_amdgcn_mfma_f32_32x32x16_f16(a1, b1, acc[1][1], 0, 0, 0);
            acc[2][1] = __builtin_amdgcn_mfma_f32_32x32x16_f16(a2, b1, acc[2][1], 0, 0, 0);
            acc[3][1] = __builtin_amdgcn_mfma_f32_32x32x16_f16(a3, b1, acc[3][1], 0, 0, 0);
        }
        __syncthreads();
    }

    // ---- epilogue (once): relu + v-weight, fold-tree over 32 j-lanes per mb ----
    const int j0 = (cls * 8 + wn * 2 + 0) * 32 + l31;
    const int j1 = (cls * 8 + wn * 2 + 1) * 32 + l31;
    const float bj0 = bk[j0], vj0 = v[j0];
    const float bj1 = bk[j1], vj1 = v[j1];

    #pragma unroll
    for (int mb = 0; mb < 4; ++mb) {
        float part[16];
        #pragma unroll
        for (int r = 0; r < 16; ++r)
            part[r] = fmaxf(acc[mb][0][r] + bj0, 0.f) * vj0
                    + fmaxf(acc[mb][1][r] + bj1, 0.f) * vj1;

        float q0[8];
        #pragma unroll
        for (int i = 0; i < 8; ++i) {
            const bool b = lane & 1;
            float keep = b ? part[i + 8] : part[i];
            float send = b ? part[i] : part[i + 8];
            q0[i] = keep + __shfl_xor(send, 1);
        }
        float q1[4];
        #pragma unroll
        for (int i = 0; i < 4; ++i) {
            const bool b = lane & 2;
            float keep = b ? q0[i + 4] : q0[i];
            float send = b ? q0[i] : q0[i + 4];
            q1[i] = keep + __shfl_xor(send, 2);
        }
        float q2[2];
        #pragma unroll
        for (int i = 0; i < 2; ++i) {
            const bool b = lane & 4;
            float keep = b ? q1[i + 2] : q1[i];
            float send = b ? q1[i] : q1[i + 2];
            q2[i] = keep + __shfl_xor(send, 4);
        }
        float q3;
        {
            const bool b = lane & 8;
            float keep = b ? q2[1] : q2[0];
            float send = b ? q2[0] : q2[1];
            q3 = keep + __shfl_xor(send, 8);
        }
        float s = q3 + __shfl_xor(q3, 16);
        if (l31 < 16) {
            const int rr  = ((l31 & 1) << 3) | ((l31 & 2) << 1) | ((l31 & 4) >> 1) | ((l31 & 8) >> 3);
            const int row = (rr & 3) + 8 * (rr >> 2) + 4 * lhi;
            scr[wm][wn][mb * 32 + row] = s;
        }
    }
    __syncthreads();

    // cross-wave (wn) sum, write 256 row-partials
    if (tid < 256) {
        const int wmx = tid >> 7;
        const int idx = tid & 127;
        float s = scr[wmx][0][idx] + scr[wmx][1][idx] + scr[wmx][2][idx] + scr[wmx][3][idx];
        partial2[(size_t)cls * ROWS + rowbase + wmx * 128 + idx] = s;
    }
}

// ---------------- K3: merge 2 classes, store logits, per-block exp-sum ----------------
__global__ void expsum_kernel(const float* __restrict__ partial2, float* __restrict__ logits,
                              float* __restrict__ blocksum) {
    __shared__ float red[256];
    const int t = threadIdx.x;
    const int row = blockIdx.x * 256 + t;
    const float lg = partial2[row] + partial2[ROWS + row];
    logits[row] = lg;
    red[t] = expf(lg);
    __syncthreads();
    for (int s = 128; s > 0; s >>= 1) {
        if (t < s) red[t] += red[t + s];
        __syncthreads();
    }
    if (t == 0) blocksum[blockIdx.x] = red[0];
}

// ---------------- K4: normalize ----------------
__global__ void norm_kernel(const float* __restrict__ logits, const float* __restrict__ blocksum,
                            float* __restrict__ out) {
    __shared__ float red[256];
    const int t = threadIdx.x;
    red[t] = blocksum[t];
    __syncthreads();
    for (int s = 128; s > 0; s >>= 1) {
        if (t < s) red[t] += red[t + s];
        __syncthreads();
    }
    const float zinv = 1.0f / red[0];
    const int i = blockIdx.x * 256 + t;
    out[i] = expf(logits[i]) * zinv;
}

extern "C" void kernel_launch(void* const* d_in, const int* in_sizes, int n_in,
                              void* d_out, int out_size, void* d_ws, size_t ws_size,
                              hipStream_t stream) {
    const float* Q    = (const float*)d_in[0];
    const float* Kmat = (const float*)d_in[1];
    const float* Wq   = (const float*)d_in[2];
    const float* bq   = (const float*)d_in[3];
    const float* Wk   = (const float*)d_in[4];
    const float* bk   = (const float*)d_in[5];
    const float* Wout = (const float*)d_in[6];
    float* out = (float*)d_out;

    char* ws = (char*)d_ws;
    _Float16* Wkf   = (_Float16*)(ws);                // 524288 B
    float* v        = (float*)(ws + 524288);          //   2048 B
    float* partial2 = (float*)(ws + 526336);          // 524288 B (2 classes x 65536)
    float* logits   = (float*)(ws + 1050624);         // 262144 B
    float* blocksum = (float*)(ws + 1312768);         //   1024 B

    hipLaunchKernelGGL(prep_kernel,   dim3(160),     dim3(256), 0, stream, Q, Wq, bq, Wout, Wk, v, Wkf);
    hipLaunchKernelGGL(score_kernel,  dim3(256, 2),  dim3(512), 0, stream, Kmat, Wkf, bk, v, partial2);
    hipLaunchKernelGGL(expsum_kernel, dim3(256),     dim3(256), 0, stream, partial2, logits, blocksum);
    hipLaunchKernelGGL(norm_kernel,   dim3(256),     dim3(256), 0, stream, logits, blocksum, out);
}